// Round 17
// baseline (192.073 us; speedup 1.0000x reference)
//
#include <hip/hip_runtime.h>
#include <math.h>

#define SEQ   2048
#define DM    1024
#define NHEAD 16
#define HD    64
#define NTOK  4096
#define EPS   1e-5f
#define SCALE_C 0.18033688f  // 0.125 * log2(e): folded into Q projection

typedef __attribute__((ext_vector_type(8))) short v8s;
typedef __attribute__((ext_vector_type(4))) short v4s;
typedef __attribute__((ext_vector_type(4))) float v4f;
typedef unsigned short ushort_t;

#define GLOAD16(g, l) __builtin_amdgcn_global_load_lds( \
    (const __attribute__((address_space(1))) unsigned int*)(g), \
    (__attribute__((address_space(3))) unsigned int*)(l), 16, 0, 0)

// K=16 bf16 MFMA: B-frag layout (k=quad*4+e, n=lane&15) matches 16x16 C-layout,
// so QK scores feed PV directly from registers.
#if defined(__has_builtin)
#if __has_builtin(__builtin_amdgcn_mfma_f32_16x16x16_bf16)
#define MFMA16(va, vb, vc) __builtin_amdgcn_mfma_f32_16x16x16_bf16(va, vb, vc, 0, 0, 0)
#elif __has_builtin(__builtin_amdgcn_mfma_f32_16x16x16bf16_1k)
#define MFMA16(va, vb, vc) __builtin_amdgcn_mfma_f32_16x16x16bf16_1k(va, vb, vc, 0, 0, 0)
#endif
#endif
#ifndef MFMA16
__device__ __forceinline__ v4f mfma16_asm(v4s a, v4s b, v4f c) {
  asm volatile("s_nop 2\n\tv_mfma_f32_16x16x16_bf16 %0, %1, %2, %0\n\ts_nop 4"
               : "+v"(c) : "v"(a), "v"(b));
  return c;
}
#define MFMA16(va, vb, vc) mfma16_asm(va, vb, vc)
#endif

__device__ __forceinline__ unsigned short f2bf(float f) {
  union { float f; unsigned u; } v; v.f = f;
  unsigned r = v.u + 0x7FFFu + ((v.u >> 16) & 1u);
  return (unsigned short)(r >> 16);
}

// pack two fp32 -> bf16x2 dword (round-half-up): 2 adds + 1 v_perm
__device__ __forceinline__ unsigned pack2_bf16(float a, float b) {
  union { float f; unsigned u; } ua, ub;
  ua.f = a; ub.f = b;
  return __builtin_amdgcn_perm(ub.u + 0x8000u, ua.u + 0x8000u, 0x07060302u);
}

// ---------------- prep: LayerNorm (blocks 0..NTOK-1) + weight transpose ----------------
__global__ __launch_bounds__(256) void prep_kernel(
    const float* __restrict__ x, const float* __restrict__ g,
    const float* __restrict__ be, ushort_t* __restrict__ y,
    const float* __restrict__ w0, const float* __restrict__ w1,
    const float* __restrict__ w2, const float* __restrict__ w3,
    ushort_t* __restrict__ o0, ushort_t* __restrict__ o1,
    ushort_t* __restrict__ o2, ushort_t* __restrict__ o3) {
  __shared__ float red[8];
  __shared__ float mu_s, rs_s;
  __shared__ float tile[64][65];
  const int t = threadIdx.x;
  if (blockIdx.x < NTOK) {
    const int row = blockIdx.x;
    const float4 v = ((const float4*)(x + (size_t)row * DM))[t];
    float s  = v.x + v.y + v.z + v.w;
    float ss = v.x*v.x + v.y*v.y + v.z*v.z + v.w*v.w;
    #pragma unroll
    for (int off = 32; off > 0; off >>= 1) {
      s  += __shfl_down(s,  off, 64);
      ss += __shfl_down(ss, off, 64);
    }
    const int wid = t >> 6, lane = t & 63;
    if (lane == 0) { red[wid] = s; red[4 + wid] = ss; }
    __syncthreads();
    if (t == 0) {
      const float S  = red[0] + red[1] + red[2] + red[3];
      const float SS = red[4] + red[5] + red[6] + red[7];
      const float mu  = S * (1.0f / DM);
      const float var = SS * (1.0f / DM) - mu * mu;
      mu_s = mu; rs_s = rsqrtf(var + EPS);
    }
    __syncthreads();
    const float mu = mu_s, r = rs_s;
    const float4 gv = ((const float4*)g)[t];
    const float4 bv = ((const float4*)be)[t];
    ushort4 o;
    o.x = f2bf((v.x - mu) * r * gv.x + bv.x);
    o.y = f2bf((v.y - mu) * r * gv.y + bv.y);
    o.z = f2bf((v.z - mu) * r * gv.z + bv.z);
    o.w = f2bf((v.w - mu) * r * gv.w + bv.w);
    *(ushort4*)(y + (size_t)row * DM + t * 4) = o;
  } else {
    const int i = blockIdx.x - NTOK;           // 0..1023
    const int z = i >> 8;
    const float* w = (z==0) ? w0 : (z==1) ? w1 : (z==2) ? w2 : w3;
    ushort_t* o    = (z==0) ? o0 : (z==1) ? o1 : (z==2) ? o2 : o3;
    const int n0 = (i & 15) * 64, k0 = ((i >> 4) & 15) * 64;
    const int r = t >> 4, c4 = (t & 15) * 4;
    #pragma unroll
    for (int ii = 0; ii < 4; ++ii) {
      const float4 v = *(const float4*)(w + (size_t)(k0 + r + ii*16) * DM + n0 + c4);
      tile[r + ii*16][c4 + 0] = v.x;
      tile[r + ii*16][c4 + 1] = v.y;
      tile[r + ii*16][c4 + 2] = v.z;
      tile[r + ii*16][c4 + 3] = v.w;
    }
    __syncthreads();
    #pragma unroll
    for (int ii = 0; ii < 4; ++ii) {
      const int n = r + ii*16;
      ushort4 o4;
      o4.x = f2bf(tile[c4 + 0][n]);
      o4.y = f2bf(tile[c4 + 1][n]);
      o4.z = f2bf(tile[c4 + 2][n]);
      o4.w = f2bf(tile[c4 + 3][n]);
      *(ushort4*)(o + (size_t)(n0 + n) * DM + k0 + c4) = o4;
    }
  }
}

// ---------------- bf16 MFMA GEMM mainloop: BK=64, 128x128 tile ----------------
__device__ __forceinline__ void gemm_main(ushort_t* lsa, ushort_t* lsb,
    const ushort_t* A, const ushort_t* WT, int m0, int n0, v4f acc[4][4]) {
  const int tid = threadIdx.x;
  const int wid = tid >> 6, lane = tid & 63;
  const int mh = (wid & 1) << 6, nh = (wid >> 1) << 6;
  const int r16 = lane & 15, quad = lane >> 4;
  const int srow = lane >> 2, sch = lane & 3;
  for (int k0 = 0; k0 < DM; k0 += 64) {
    __syncthreads();
    #pragma unroll
    for (int s = 0; s < 2; ++s) {
      #pragma unroll
      for (int j = 0; j < 2; ++j) {
        const int o = wid * 2 + j;
        GLOAD16(A  + (size_t)(m0 + o*16 + srow) * DM + k0 + s*32 + sch*8, lsa + s*4096 + o*512);
        GLOAD16(WT + (size_t)(n0 + o*16 + srow) * DM + k0 + s*32 + sch*8, lsb + s*4096 + o*512);
      }
    }
    __syncthreads();
    #pragma unroll
    for (int s = 0; s < 2; ++s) {
      v8s af[4], bfr[4];
      #pragma unroll
      for (int i = 0; i < 4; ++i) {
        af[i]  = *(const v8s*)(lsa + s*4096 + (mh + i*16 + r16)*32 + quad*8);
        bfr[i] = *(const v8s*)(lsb + s*4096 + (nh + i*16 + r16)*32 + quad*8);
      }
      #pragma unroll
      for (int i = 0; i < 4; ++i)
        #pragma unroll
        for (int j = 0; j < 4; ++j)
          acc[i][j] = __builtin_amdgcn_mfma_f32_16x16x32_bf16(af[i], bfr[j], acc[i][j], 0, 0, 0);
    }
  }
}

// Fused QKV projections. 768 blocks = exactly 3/CU, XCD-chunk-swizzled.
// z==0 pre-scales Q by SCALE_C. z==2 writes V in PV-fragment-linear tile layout.
__global__ __launch_bounds__(256, 3) void gemm_qkv(const ushort_t* __restrict__ xn,
    const ushort_t* __restrict__ wtq, const ushort_t* __restrict__ wtk, const ushort_t* __restrict__ wtv,
    const float* __restrict__ bq, const float* __restrict__ bk, const float* __restrict__ bv,
    ushort_t* __restrict__ qo, ushort_t* __restrict__ ko, ushort_t* __restrict__ vto) {
  __shared__ ushort_t lsa[128*64];
  __shared__ ushort_t lsb[128*64];
  // T1: flat id -> contiguous chunk per XCD (768 = 8 XCDs x 96 tiles)
  const int flat = blockIdx.x;
  const int nf = (flat & 7) * 96 + (flat >> 3);
  const int zi = nf >> 8;                 // 0..2  weight select
  const int yi = (nf >> 3) & 31;          // M-tile
  const int xi = nf & 7;                  // N-tile
  const ushort_t* WT = (zi == 0) ? wtq : (zi == 1) ? wtk : wtv;
  const float* bias  = (zi == 0) ? bq  : (zi == 1) ? bk  : bv;
  const int m0 = yi * 128, n0 = xi * 128;
  v4f acc[4][4];
  #pragma unroll
  for (int i = 0; i < 4; ++i)
    #pragma unroll
    for (int j = 0; j < 4; ++j) acc[i][j] = (v4f){0.f, 0.f, 0.f, 0.f};
  gemm_main(lsa, lsb, xn, WT, m0, n0, acc);
  const int tid = threadIdx.x, wid = tid >> 6, lane = tid & 63;
  const int mh = (wid & 1) << 6, nh = (wid >> 1) << 6;
  const int r16 = lane & 15, quad = lane >> 4;
  if (zi < 2) {
    ushort_t* out = (zi == 0) ? qo : ko;
    const float sc = (zi == 0) ? SCALE_C : 1.0f;
    #pragma unroll
    for (int bn = 0; bn < 4; ++bn) {
      const int col = n0 + nh + bn*16 + r16;
      const float bb = bias[col];
      #pragma unroll
      for (int am = 0; am < 4; ++am) {
        const int tb = m0 + mh + am*16 + quad*4;
        #pragma unroll
        for (int r = 0; r < 4; ++r)
          out[(size_t)(tb + r) * DM + col] = f2bf((acc[am][bn][r] + bb) * sc);
      }
    }
  } else {
    #pragma unroll
    for (int bn = 0; bn < 4; ++bn) {
      const int col = n0 + nh + bn*16 + r16;
      const float bb = bias[col];
      const int h = col >> 6, d = col & 63;
      #pragma unroll
      for (int am = 0; am < 4; ++am) {
        const int tb = m0 + mh + am*16 + quad*4;
        const int b = tb >> 11, t = tb & 2047;   // t % 4 == 0
        const int bh = b * NHEAD + h;
        ushort4 o4;
        o4.x = f2bf(acc[am][bn][0] + bb);
        o4.y = f2bf(acc[am][bn][1] + bb);
        o4.z = f2bf(acc[am][bn][2] + bb);
        o4.w = f2bf(acc[am][bn][3] + bb);
        const size_t idx = (size_t)bh * 131072 + (size_t)(t >> 6) * 4096 +
                           (size_t)((((t >> 4) & 3) * 4) + (d >> 4)) * 256 +
                           ((t >> 2) & 3) * 64 + (d & 15) * 4;
        *(ushort4*)(vto + idx) = o4;
      }
    }
  }
}

// Output projection: fp32 out = A @ WTo^T + bo.
// BM=128, BN=64 -> 512 blocks = 2/CU all-resident, XCD-chunk-swizzled.
__global__ __launch_bounds__(256, 2) void gemm_out(const ushort_t* __restrict__ A,
    const ushort_t* __restrict__ WT, const float* __restrict__ bias,
    float* __restrict__ out) {
  __shared__ ushort_t lsa[128*64];   // 16 KiB
  __shared__ ushort_t lsb[64*64];    // 8 KiB
  const int flat = blockIdx.x;
  const int nf = (flat & 7) * 64 + (flat >> 3);   // 512 = 8 x 64
  const int n0 = (nf & 15) * 64, m0 = (nf >> 4) * 128;
  const int tid = threadIdx.x;
  const int wid = tid >> 6, lane = tid & 63;
  const int mh = (wid & 1) << 6, nh = (wid >> 1) << 5;   // wave tile 64x32
  const int r16 = lane & 15, quad = lane >> 4;
  const int srow = lane >> 2, sch = lane & 3;
  v4f acc[4][2];
  #pragma unroll
  for (int i = 0; i < 4; ++i)
    #pragma unroll
    for (int j = 0; j < 2; ++j) acc[i][j] = (v4f){0.f, 0.f, 0.f, 0.f};
  for (int k0 = 0; k0 < DM; k0 += 64) {
    __syncthreads();
    #pragma unroll
    for (int s = 0; s < 2; ++s) {
      #pragma unroll
      for (int j = 0; j < 2; ++j) {
        const int o = wid * 2 + j;
        GLOAD16(A + (size_t)(m0 + o*16 + srow) * DM + k0 + s*32 + sch*8, lsa + s*4096 + o*512);
      }
      // B: 64 rows -> 4 chunks, one per wave
      GLOAD16(WT + (size_t)(n0 + wid*16 + srow) * DM + k0 + s*32 + sch*8, lsb + s*2048 + wid*512);
    }
    __syncthreads();
    #pragma unroll
    for (int s = 0; s < 2; ++s) {
      v8s af[4], bfr[2];
      #pragma unroll
      for (int i = 0; i < 4; ++i)
        af[i] = *(const v8s*)(lsa + s*4096 + (mh + i*16 + r16)*32 + quad*8);
      #pragma unroll
      for (int j = 0; j < 2; ++j)
        bfr[j] = *(const v8s*)(lsb + s*2048 + (nh + j*16 + r16)*32 + quad*8);
      #pragma unroll
      for (int i = 0; i < 4; ++i)
        #pragma unroll
        for (int j = 0; j < 2; ++j)
          acc[i][j] = __builtin_amdgcn_mfma_f32_16x16x32_bf16(af[i], bfr[j], acc[i][j], 0, 0, 0);
    }
  }
  #pragma unroll
  for (int bn = 0; bn < 2; ++bn) {
    const int col = n0 + nh + bn*16 + r16;
    const float bb = bias[col];
    #pragma unroll
    for (int am = 0; am < 4; ++am) {
      const int tb = m0 + mh + am*16 + quad*4;
      #pragma unroll
      for (int r = 0; r < 4; ++r)
        out[(size_t)(tb + r) * DM + col] = acc[am][bn][r] + bb;
    }
  }
}

// ---------------- MFMA flash attention v17 (FROZEN): v12 loop + pad + XCD head-affinity ----------------
// Best attn measured: 54.4 µs, FETCH 12.3 MB (K/V L2-resident per XCD),
// conflicts 0, MfmaUtil+VALU ~75% combined. Structure at its floor.
#define FSTR 66
__global__ __launch_bounds__(512, 4) void attn_kernel(
    const ushort_t* __restrict__ Q, const ushort_t* __restrict__ K,
    const ushort_t* __restrict__ Vt, ushort_t* __restrict__ O) {
  // staging view: [K h0 | K h1 | V h0 | V h1], 4 x 8 KiB (32 KiB)
  // epilogue view: fp32[128][FSTR] = 33792 B
  __shared__ ushort_t smem[16896];
  __shared__ float lred[128];
  const int tid = threadIdx.x, wid = tid >> 6, lane = tid & 63;
  const int r16 = lane & 15, quad = lane >> 4;
  const int w4 = wid & 3, half = wid >> 2;
  // XCD head-affinity: flat -> (xcd = flat&7), bh = xcd*4 + (rest>>4), q = rest&15
  const int flat = blockIdx.x;
  const int xcd = flat & 7, rest = flat >> 3;
  const int bh = xcd * 4 + (rest >> 4);
  const int q0 = (rest & 15) * 128;
  const int b = bh >> 4, h = bh & 15;
  const ushort_t* gQ = Q + (size_t)b * SEQ * DM + h * HD;
  const ushort_t* gK = K + (size_t)b * SEQ * DM + h * HD;
  const ushort_t* gV = Vt + (size_t)bh * 131072;

  ushort_t* kb = smem + half * 4096;          // this half's K tile (8 KiB)
  ushort_t* vb = smem + 8192 + half * 4096;   // this half's V tile (8 KiB)

  const int qt0 = q0 + w4 * 32 + r16;         // q-group 0 token
  const int qt1 = qt0 + 16;                   // q-group 1 token
  const v8s qf00 = *(const v8s*)(gQ + (size_t)qt0 * DM + quad * 8);
  const v8s qf01 = *(const v8s*)(gQ + (size_t)qt0 * DM + 32 + quad * 8);
  const v8s qf10 = *(const v8s*)(gQ + (size_t)qt1 * DM + quad * 8);
  const v8s qf11 = *(const v8s*)(gQ + (size_t)qt1 * DM + 32 + quad * 8);
  v4f acc0[4], acc1[4];
  #pragma unroll
  for (int i = 0; i < 4; ++i) {
    acc0[i] = (v4f){0.f, 0.f, 0.f, 0.f};
    acc1[i] = (v4f){0.f, 0.f, 0.f, 0.f};
  }
  float lrun0 = 0.f, lrun1 = 0.f;

  const int NIT = SEQ / 128;                  // 16 key-tiles of 64 per half
  const int kt0 = half * NIT;
  const int o0 = w4 * 2, o1 = o0 + 1;
  const ushort_t* srcK0 = gK + (size_t)((o0 >> 1) * 16 + r16) * DM + (o0 & 1) * 32 + quad * 8;
  const ushort_t* srcK1 = gK + (size_t)((o1 >> 1) * 16 + r16) * DM + (o1 & 1) * 32 + quad * 8;
  const ushort_t* srcV  = gV + lane * 8;

  for (int it = 0; it < NIT; ++it) {
    const int kt = kt0 + it;
    const int k0 = kt * 64;
    __syncthreads();   // previous tile's reads done; buffers reusable
    GLOAD16(srcK0 + (size_t)k0 * DM, kb + o0 * 512);
    GLOAD16(srcK1 + (size_t)k0 * DM, kb + o1 * 512);
    GLOAD16(srcV + (size_t)kt * 4096 + o0 * 512, vb + o0 * 512);
    GLOAD16(srcV + (size_t)kt * 4096 + o1 * 512, vb + o1 * 512);
    __syncthreads();   // staged data visible (barrier drains vmcnt)

    // S^T = K.Q^T for both q-groups: 16 MFMA, ka fragments shared
    v4f s0[4], s1[4];
    #pragma unroll
    for (int g = 0; g < 4; ++g) {
      s0[g] = (v4f){0.f, 0.f, 0.f, 0.f};
      s1[g] = (v4f){0.f, 0.f, 0.f, 0.f};
    }
    #pragma unroll
    for (int g = 0; g < 4; ++g) {
      const v8s ka0 = *(const v8s*)(kb + (g*2 + 0) * 512 + lane * 8);
      const v8s ka1 = *(const v8s*)(kb + (g*2 + 1) * 512 + lane * 8);
      s0[g] = __builtin_amdgcn_mfma_f32_16x16x32_bf16(ka0, qf00, s0[g], 0, 0, 0);
      s0[g] = __builtin_amdgcn_mfma_f32_16x16x32_bf16(ka1, qf01, s0[g], 0, 0, 0);
      s1[g] = __builtin_amdgcn_mfma_f32_16x16x32_bf16(ka0, qf10, s1[g], 0, 0, 0);
      s1[g] = __builtin_amdgcn_mfma_f32_16x16x32_bf16(ka1, qf11, s1[g], 0, 0, 0);
    }

    // no-max softmax (exp2 domain) -> in-register PV B-fragments, both groups
    v4s pf0[4], pf1[4];
    float ls0 = 0.f, ls1 = 0.f;
    #pragma unroll
    for (int g = 0; g < 4; ++g) {
      float e0 = __builtin_amdgcn_exp2f(s0[g][0]);
      float e1 = __builtin_amdgcn_exp2f(s0[g][1]);
      float e2 = __builtin_amdgcn_exp2f(s0[g][2]);
      float e3 = __builtin_amdgcn_exp2f(s0[g][3]);
      ls0 += (e0 + e1) + (e2 + e3);
      union { v4s s; uint2 u; } pk;
      pk.u.x = pack2_bf16(e0, e1);
      pk.u.y = pack2_bf16(e2, e3);
      pf0[g] = pk.s;
      float f0 = __builtin_amdgcn_exp2f(s1[g][0]);
      float f1 = __builtin_amdgcn_exp2f(s1[g][1]);
      float f2 = __builtin_amdgcn_exp2f(s1[g][2]);
      float f3 = __builtin_amdgcn_exp2f(s1[g][3]);
      ls1 += (f0 + f1) + (f2 + f3);
      union { v4s s; uint2 u; } pk2;
      pk2.u.x = pack2_bf16(f0, f1);
      pk2.u.y = pack2_bf16(f2, f3);
      pf1[g] = pk2.s;
    }
    ls0 += __shfl_xor(ls0, 16, 64);
    ls0 += __shfl_xor(ls0, 32, 64);
    lrun0 += ls0;
    ls1 += __shfl_xor(ls1, 16, 64);
    ls1 += __shfl_xor(ls1, 32, 64);
    lrun1 += ls1;

    // O^T += V^T . P : 32 MFMA (16x16x16), vf fragments shared across groups
    #pragma unroll
    for (int dg = 0; dg < 4; ++dg) {
      #pragma unroll
      for (int g = 0; g < 4; ++g) {
        const v4s vf = *(const v4s*)(vb + (g*4 + dg) * 256 + quad * 64 + r16 * 4);
        acc0[dg] = MFMA16(vf, pf0[g], acc0[dg]);
        acc1[dg] = MFMA16(vf, pf1[g], acc1[dg]);
      }
    }
  }

  // ---- in-LDS cross-half combine (rows padded to FSTR floats: conflict-free) ----
  __syncthreads();   // all waves done with K/V LDS
  float* facc = (float*)smem;
  const int row0 = w4 * 32 + r16, row1 = row0 + 16;
  if (half == 1) {
    #pragma unroll
    for (int dg = 0; dg < 4; ++dg) {
      *(v4f*)(facc + row0 * FSTR + dg * 16 + quad * 4) = acc0[dg];
      *(v4f*)(facc + row1 * FSTR + dg * 16 + quad * 4) = acc1[dg];
    }
    if (quad == 0) { lred[row0] = lrun0; lred[row1] = lrun1; }
  }
  __syncthreads();
  if (half == 0) {
    const float inv0 = 1.f / (lrun0 + lred[row0]);
    const float inv1 = 1.f / (lrun1 + lred[row1]);
    ushort_t* gO = O + (size_t)b * SEQ * DM + h * HD;
    #pragma unroll
    for (int dg = 0; dg < 4; ++dg) {
      const v4f u0 = acc0[dg] + *(const v4f*)(facc + row0 * FSTR + dg * 16 + quad * 4);
      const v4f u1 = acc1[dg] + *(const v4f*)(facc + row1 * FSTR + dg * 16 + quad * 4);
      ushort4 o4;
      o4.x = f2bf(u0[0] * inv0);
      o4.y = f2bf(u0[1] * inv0);
      o4.z = f2bf(u0[2] * inv0);
      o4.w = f2bf(u0[3] * inv0);
      *(ushort4*)(gO + (size_t)qt0 * DM + dg*16 + quad*4) = o4;
      ushort4 o5;
      o5.x = f2bf(u1[0] * inv1);
      o5.y = f2bf(u1[1] * inv1);
      o5.z = f2bf(u1[2] * inv1);
      o5.w = f2bf(u1[3] * inv1);
      *(ushort4*)(gO + (size_t)qt1 * DM + dg*16 + quad*4) = o5;
    }
  }
}

extern "C" void kernel_launch(void* const* d_in, const int* in_sizes, int n_in,
                              void* d_out, int out_size, void* d_ws, size_t ws_size,
                              hipStream_t stream) {
  const float* x     = (const float*)d_in[0];
  const float* gamma = (const float*)d_in[1];
  const float* beta  = (const float*)d_in[2];
  const float* wq    = (const float*)d_in[3];
  const float* bq    = (const float*)d_in[4];
  const float* wk    = (const float*)d_in[5];
  const float* bk    = (const float*)d_in[6];
  const float* wv    = (const float*)d_in[7];
  const float* bv    = (const float*)d_in[8];
  const float* wo    = (const float*)d_in[9];
  const float* bo    = (const float*)d_in[10];
  float* out = (float*)d_out;

  unsigned char* w8 = (unsigned char*)d_ws;
  const size_t MB = 1024 * 1024;
  ushort_t* xn  = (ushort_t*)(w8 + 0 * MB);   // 8 MB; reused as attention output
  ushort_t* qb  = (ushort_t*)(w8 + 8 * MB);
  ushort_t* kb  = (ushort_t*)(w8 + 16 * MB);
  ushort_t* vt  = (ushort_t*)(w8 + 24 * MB);
  ushort_t* wtq = (ushort_t*)(w8 + 32 * MB);
  ushort_t* wtk = (ushort_t*)(w8 + 34 * MB);
  ushort_t* wtv = (ushort_t*)(w8 + 36 * MB);
  ushort_t* wto = (ushort_t*)(w8 + 38 * MB);
  ushort_t* ob  = xn;

  prep_kernel<<<dim3(NTOK + 1024), dim3(256), 0, stream>>>(
      x, gamma, beta, xn, wq, wk, wv, wo, wtq, wtk, wtv, wto);
  gemm_qkv<<<dim3(768), dim3(256), 0, stream>>>(xn, wtq, wtk, wtv, bq, bk, bv, qb, kb, vt);
  attn_kernel<<<dim3(512), dim3(512), 0, stream>>>(qb, kb, vt, ob);
  gemm_out<<<dim3(512), dim3(256), 0, stream>>>(ob, wto, bo, out);
}

// Round 18
// 189.289 us; speedup vs baseline: 1.0147x; 1.0147x over previous
//
#include <hip/hip_runtime.h>
#include <math.h>

#define SEQ   2048
#define DM    1024
#define NHEAD 16
#define HD    64
#define NTOK  4096
#define EPS   1e-5f
#define SCALE_C 0.18033688f  // 0.125 * log2(e): folded into Q projection

typedef __attribute__((ext_vector_type(8))) short v8s;
typedef __attribute__((ext_vector_type(4))) short v4s;
typedef __attribute__((ext_vector_type(4))) float v4f;
typedef unsigned short ushort_t;

#define GLOAD16(g, l) __builtin_amdgcn_global_load_lds( \
    (const __attribute__((address_space(1))) unsigned int*)(g), \
    (__attribute__((address_space(3))) unsigned int*)(l), 16, 0, 0)

// K=16 bf16 MFMA: B-frag layout (k=quad*4+e, n=lane&15) matches 16x16 C-layout,
// so QK scores feed PV directly from registers.
#if defined(__has_builtin)
#if __has_builtin(__builtin_amdgcn_mfma_f32_16x16x16_bf16)
#define MFMA16(va, vb, vc) __builtin_amdgcn_mfma_f32_16x16x16_bf16(va, vb, vc, 0, 0, 0)
#elif __has_builtin(__builtin_amdgcn_mfma_f32_16x16x16bf16_1k)
#define MFMA16(va, vb, vc) __builtin_amdgcn_mfma_f32_16x16x16bf16_1k(va, vb, vc, 0, 0, 0)
#endif
#endif
#ifndef MFMA16
__device__ __forceinline__ v4f mfma16_asm(v4s a, v4s b, v4f c) {
  asm volatile("s_nop 2\n\tv_mfma_f32_16x16x16_bf16 %0, %1, %2, %0\n\ts_nop 4"
               : "+v"(c) : "v"(a), "v"(b));
  return c;
}
#define MFMA16(va, vb, vc) mfma16_asm(va, vb, vc)
#endif

__device__ __forceinline__ unsigned short f2bf(float f) {
  union { float f; unsigned u; } v; v.f = f;
  unsigned r = v.u + 0x7FFFu + ((v.u >> 16) & 1u);
  return (unsigned short)(r >> 16);
}

// pack two fp32 -> bf16x2 dword (round-half-up): 2 adds + 1 v_perm
__device__ __forceinline__ unsigned pack2_bf16(float a, float b) {
  union { float f; unsigned u; } ua, ub;
  ua.f = a; ub.f = b;
  return __builtin_amdgcn_perm(ub.u + 0x8000u, ua.u + 0x8000u, 0x07060302u);
}

// ---------------- prep: LayerNorm (blocks 0..NTOK-1) + weight transpose ----------------
__global__ __launch_bounds__(256) void prep_kernel(
    const float* __restrict__ x, const float* __restrict__ g,
    const float* __restrict__ be, ushort_t* __restrict__ y,
    const float* __restrict__ w0, const float* __restrict__ w1,
    const float* __restrict__ w2, const float* __restrict__ w3,
    ushort_t* __restrict__ o0, ushort_t* __restrict__ o1,
    ushort_t* __restrict__ o2, ushort_t* __restrict__ o3) {
  __shared__ float red[8];
  __shared__ float mu_s, rs_s;
  __shared__ float tile[64][65];
  const int t = threadIdx.x;
  if (blockIdx.x < NTOK) {
    const int row = blockIdx.x;
    const float4 v = ((const float4*)(x + (size_t)row * DM))[t];
    float s  = v.x + v.y + v.z + v.w;
    float ss = v.x*v.x + v.y*v.y + v.z*v.z + v.w*v.w;
    #pragma unroll
    for (int off = 32; off > 0; off >>= 1) {
      s  += __shfl_down(s,  off, 64);
      ss += __shfl_down(ss, off, 64);
    }
    const int wid = t >> 6, lane = t & 63;
    if (lane == 0) { red[wid] = s; red[4 + wid] = ss; }
    __syncthreads();
    if (t == 0) {
      const float S  = red[0] + red[1] + red[2] + red[3];
      const float SS = red[4] + red[5] + red[6] + red[7];
      const float mu  = S * (1.0f / DM);
      const float var = SS * (1.0f / DM) - mu * mu;
      mu_s = mu; rs_s = rsqrtf(var + EPS);
    }
    __syncthreads();
    const float mu = mu_s, r = rs_s;
    const float4 gv = ((const float4*)g)[t];
    const float4 bv = ((const float4*)be)[t];
    ushort4 o;
    o.x = f2bf((v.x - mu) * r * gv.x + bv.x);
    o.y = f2bf((v.y - mu) * r * gv.y + bv.y);
    o.z = f2bf((v.z - mu) * r * gv.z + bv.z);
    o.w = f2bf((v.w - mu) * r * gv.w + bv.w);
    *(ushort4*)(y + (size_t)row * DM + t * 4) = o;
  } else {
    const int i = blockIdx.x - NTOK;           // 0..1023
    const int z = i >> 8;
    const float* w = (z==0) ? w0 : (z==1) ? w1 : (z==2) ? w2 : w3;
    ushort_t* o    = (z==0) ? o0 : (z==1) ? o1 : (z==2) ? o2 : o3;
    const int n0 = (i & 15) * 64, k0 = ((i >> 4) & 15) * 64;
    const int r = t >> 4, c4 = (t & 15) * 4;
    #pragma unroll
    for (int ii = 0; ii < 4; ++ii) {
      const float4 v = *(const float4*)(w + (size_t)(k0 + r + ii*16) * DM + n0 + c4);
      tile[r + ii*16][c4 + 0] = v.x;
      tile[r + ii*16][c4 + 1] = v.y;
      tile[r + ii*16][c4 + 2] = v.z;
      tile[r + ii*16][c4 + 3] = v.w;
    }
    __syncthreads();
    #pragma unroll
    for (int ii = 0; ii < 4; ++ii) {
      const int n = r + ii*16;
      ushort4 o4;
      o4.x = f2bf(tile[c4 + 0][n]);
      o4.y = f2bf(tile[c4 + 1][n]);
      o4.z = f2bf(tile[c4 + 2][n]);
      o4.w = f2bf(tile[c4 + 3][n]);
      *(ushort4*)(o + (size_t)(n0 + n) * DM + k0 + c4) = o4;
    }
  }
}

// ---------------- bf16 MFMA GEMM mainloop: BK=64, 128x128 tile ----------------
__device__ __forceinline__ void gemm_main(ushort_t* lsa, ushort_t* lsb,
    const ushort_t* A, const ushort_t* WT, int m0, int n0, v4f acc[4][4]) {
  const int tid = threadIdx.x;
  const int wid = tid >> 6, lane = tid & 63;
  const int mh = (wid & 1) << 6, nh = (wid >> 1) << 6;
  const int r16 = lane & 15, quad = lane >> 4;
  const int srow = lane >> 2, sch = lane & 3;
  for (int k0 = 0; k0 < DM; k0 += 64) {
    __syncthreads();
    #pragma unroll
    for (int s = 0; s < 2; ++s) {
      #pragma unroll
      for (int j = 0; j < 2; ++j) {
        const int o = wid * 2 + j;
        GLOAD16(A  + (size_t)(m0 + o*16 + srow) * DM + k0 + s*32 + sch*8, lsa + s*4096 + o*512);
        GLOAD16(WT + (size_t)(n0 + o*16 + srow) * DM + k0 + s*32 + sch*8, lsb + s*4096 + o*512);
      }
    }
    __syncthreads();
    #pragma unroll
    for (int s = 0; s < 2; ++s) {
      v8s af[4], bfr[4];
      #pragma unroll
      for (int i = 0; i < 4; ++i) {
        af[i]  = *(const v8s*)(lsa + s*4096 + (mh + i*16 + r16)*32 + quad*8);
        bfr[i] = *(const v8s*)(lsb + s*4096 + (nh + i*16 + r16)*32 + quad*8);
      }
      #pragma unroll
      for (int i = 0; i < 4; ++i)
        #pragma unroll
        for (int j = 0; j < 4; ++j)
          acc[i][j] = __builtin_amdgcn_mfma_f32_16x16x32_bf16(af[i], bfr[j], acc[i][j], 0, 0, 0);
    }
  }
}

// Fused QKV projections. 768 blocks = exactly 3/CU, XCD-chunk-swizzled.
// z==0 pre-scales Q by SCALE_C. z==2 writes V in PV-fragment-linear tile layout.
__global__ __launch_bounds__(256, 3) void gemm_qkv(const ushort_t* __restrict__ xn,
    const ushort_t* __restrict__ wtq, const ushort_t* __restrict__ wtk, const ushort_t* __restrict__ wtv,
    const float* __restrict__ bq, const float* __restrict__ bk, const float* __restrict__ bv,
    ushort_t* __restrict__ qo, ushort_t* __restrict__ ko, ushort_t* __restrict__ vto) {
  __shared__ ushort_t lsa[128*64];
  __shared__ ushort_t lsb[128*64];
  // T1: flat id -> contiguous chunk per XCD (768 = 8 XCDs x 96 tiles)
  const int flat = blockIdx.x;
  const int nf = (flat & 7) * 96 + (flat >> 3);
  const int zi = nf >> 8;                 // 0..2  weight select
  const int yi = (nf >> 3) & 31;          // M-tile
  const int xi = nf & 7;                  // N-tile
  const ushort_t* WT = (zi == 0) ? wtq : (zi == 1) ? wtk : wtv;
  const float* bias  = (zi == 0) ? bq  : (zi == 1) ? bk  : bv;
  const int m0 = yi * 128, n0 = xi * 128;
  v4f acc[4][4];
  #pragma unroll
  for (int i = 0; i < 4; ++i)
    #pragma unroll
    for (int j = 0; j < 4; ++j) acc[i][j] = (v4f){0.f, 0.f, 0.f, 0.f};
  gemm_main(lsa, lsb, xn, WT, m0, n0, acc);
  const int tid = threadIdx.x, wid = tid >> 6, lane = tid & 63;
  const int mh = (wid & 1) << 6, nh = (wid >> 1) << 6;
  const int r16 = lane & 15, quad = lane >> 4;
  if (zi < 2) {
    ushort_t* out = (zi == 0) ? qo : ko;
    const float sc = (zi == 0) ? SCALE_C : 1.0f;
    #pragma unroll
    for (int bn = 0; bn < 4; ++bn) {
      const int col = n0 + nh + bn*16 + r16;
      const float bb = bias[col];
      #pragma unroll
      for (int am = 0; am < 4; ++am) {
        const int tb = m0 + mh + am*16 + quad*4;
        #pragma unroll
        for (int r = 0; r < 4; ++r)
          out[(size_t)(tb + r) * DM + col] = f2bf((acc[am][bn][r] + bb) * sc);
      }
    }
  } else {
    #pragma unroll
    for (int bn = 0; bn < 4; ++bn) {
      const int col = n0 + nh + bn*16 + r16;
      const float bb = bias[col];
      const int h = col >> 6, d = col & 63;
      #pragma unroll
      for (int am = 0; am < 4; ++am) {
        const int tb = m0 + mh + am*16 + quad*4;
        const int b = tb >> 11, t = tb & 2047;   // t % 4 == 0
        const int bh = b * NHEAD + h;
        ushort4 o4;
        o4.x = f2bf(acc[am][bn][0] + bb);
        o4.y = f2bf(acc[am][bn][1] + bb);
        o4.z = f2bf(acc[am][bn][2] + bb);
        o4.w = f2bf(acc[am][bn][3] + bb);
        const size_t idx = (size_t)bh * 131072 + (size_t)(t >> 6) * 4096 +
                           (size_t)((((t >> 4) & 3) * 4) + (d >> 4)) * 256 +
                           ((t >> 2) & 3) * 64 + (d & 15) * 4;
        *(ushort4*)(vto + idx) = o4;
      }
    }
  }
}

// Output projection: fp32 out = A @ WTo^T + bo.
// v2: BM=64, BN=64 -> 1024 blocks = 4/CU all-resident (residency lever: the
// session's most reliable win). LDS 16 KiB; wave tile 32x32 (acc 2x2).
// XCD-chunk-swizzled (128 tiles/XCD). A re-reads rise 8->16x but stay in L2/L3.
__global__ __launch_bounds__(256, 4) void gemm_out(const ushort_t* __restrict__ A,
    const ushort_t* __restrict__ WT, const float* __restrict__ bias,
    float* __restrict__ out) {
  __shared__ ushort_t lsa[64*64];    // 8 KiB
  __shared__ ushort_t lsb[64*64];    // 8 KiB
  const int flat = blockIdx.x;
  const int nf = (flat & 7) * 128 + (flat >> 3);   // 1024 = 8 x 128, bijective
  const int n0 = (nf & 15) * 64, m0 = (nf >> 4) * 64;
  const int tid = threadIdx.x;
  const int wid = tid >> 6, lane = tid & 63;
  const int mh = (wid & 1) << 5, nh = (wid >> 1) << 5;   // wave tile 32x32
  const int r16 = lane & 15, quad = lane >> 4;
  const int srow = lane >> 2, sch = lane & 3;
  v4f acc[2][2];
  #pragma unroll
  for (int i = 0; i < 2; ++i)
    #pragma unroll
    for (int j = 0; j < 2; ++j) acc[i][j] = (v4f){0.f, 0.f, 0.f, 0.f};
  for (int k0 = 0; k0 < DM; k0 += 64) {
    __syncthreads();
    #pragma unroll
    for (int s = 0; s < 2; ++s) {
      // A: 64 rows -> 4 chunks (16 rows x 32 cols), one per wave
      GLOAD16(A  + (size_t)(m0 + wid*16 + srow) * DM + k0 + s*32 + sch*8, lsa + s*2048 + wid*512);
      // B: 64 rows -> 4 chunks, one per wave
      GLOAD16(WT + (size_t)(n0 + wid*16 + srow) * DM + k0 + s*32 + sch*8, lsb + s*2048 + wid*512);
    }
    __syncthreads();
    #pragma unroll
    for (int s = 0; s < 2; ++s) {
      v8s af[2], bfr[2];
      #pragma unroll
      for (int i = 0; i < 2; ++i)
        af[i] = *(const v8s*)(lsa + s*2048 + (mh + i*16 + r16)*32 + quad*8);
      #pragma unroll
      for (int j = 0; j < 2; ++j)
        bfr[j] = *(const v8s*)(lsb + s*2048 + (nh + j*16 + r16)*32 + quad*8);
      #pragma unroll
      for (int i = 0; i < 2; ++i)
        #pragma unroll
        for (int j = 0; j < 2; ++j)
          acc[i][j] = __builtin_amdgcn_mfma_f32_16x16x32_bf16(af[i], bfr[j], acc[i][j], 0, 0, 0);
    }
  }
  #pragma unroll
  for (int bn = 0; bn < 2; ++bn) {
    const int col = n0 + nh + bn*16 + r16;
    const float bb = bias[col];
    #pragma unroll
    for (int am = 0; am < 2; ++am) {
      const int tb = m0 + mh + am*16 + quad*4;
      #pragma unroll
      for (int r = 0; r < 4; ++r)
        out[(size_t)(tb + r) * DM + col] = acc[am][bn][r] + bb;
    }
  }
}

// ---------------- MFMA flash attention v17 (FROZEN): v12 loop + pad + XCD head-affinity ----------------
// Best attn measured: 54.4 µs, FETCH 12.3 MB (K/V L2-resident per XCD),
// conflicts 0, MfmaUtil+VALU ~75% combined. Structure at its floor.
#define FSTR 66
__global__ __launch_bounds__(512, 4) void attn_kernel(
    const ushort_t* __restrict__ Q, const ushort_t* __restrict__ K,
    const ushort_t* __restrict__ Vt, ushort_t* __restrict__ O) {
  // staging view: [K h0 | K h1 | V h0 | V h1], 4 x 8 KiB (32 KiB)
  // epilogue view: fp32[128][FSTR] = 33792 B
  __shared__ ushort_t smem[16896];
  __shared__ float lred[128];
  const int tid = threadIdx.x, wid = tid >> 6, lane = tid & 63;
  const int r16 = lane & 15, quad = lane >> 4;
  const int w4 = wid & 3, half = wid >> 2;
  // XCD head-affinity: flat -> (xcd = flat&7), bh = xcd*4 + (rest>>4), q = rest&15
  const int flat = blockIdx.x;
  const int xcd = flat & 7, rest = flat >> 3;
  const int bh = xcd * 4 + (rest >> 4);
  const int q0 = (rest & 15) * 128;
  const int b = bh >> 4, h = bh & 15;
  const ushort_t* gQ = Q + (size_t)b * SEQ * DM + h * HD;
  const ushort_t* gK = K + (size_t)b * SEQ * DM + h * HD;
  const ushort_t* gV = Vt + (size_t)bh * 131072;

  ushort_t* kb = smem + half * 4096;          // this half's K tile (8 KiB)
  ushort_t* vb = smem + 8192 + half * 4096;   // this half's V tile (8 KiB)

  const int qt0 = q0 + w4 * 32 + r16;         // q-group 0 token
  const int qt1 = qt0 + 16;                   // q-group 1 token
  const v8s qf00 = *(const v8s*)(gQ + (size_t)qt0 * DM + quad * 8);
  const v8s qf01 = *(const v8s*)(gQ + (size_t)qt0 * DM + 32 + quad * 8);
  const v8s qf10 = *(const v8s*)(gQ + (size_t)qt1 * DM + quad * 8);
  const v8s qf11 = *(const v8s*)(gQ + (size_t)qt1 * DM + 32 + quad * 8);
  v4f acc0[4], acc1[4];
  #pragma unroll
  for (int i = 0; i < 4; ++i) {
    acc0[i] = (v4f){0.f, 0.f, 0.f, 0.f};
    acc1[i] = (v4f){0.f, 0.f, 0.f, 0.f};
  }
  float lrun0 = 0.f, lrun1 = 0.f;

  const int NIT = SEQ / 128;                  // 16 key-tiles of 64 per half
  const int kt0 = half * NIT;
  const int o0 = w4 * 2, o1 = o0 + 1;
  const ushort_t* srcK0 = gK + (size_t)((o0 >> 1) * 16 + r16) * DM + (o0 & 1) * 32 + quad * 8;
  const ushort_t* srcK1 = gK + (size_t)((o1 >> 1) * 16 + r16) * DM + (o1 & 1) * 32 + quad * 8;
  const ushort_t* srcV  = gV + lane * 8;

  for (int it = 0; it < NIT; ++it) {
    const int kt = kt0 + it;
    const int k0 = kt * 64;
    __syncthreads();   // previous tile's reads done; buffers reusable
    GLOAD16(srcK0 + (size_t)k0 * DM, kb + o0 * 512);
    GLOAD16(srcK1 + (size_t)k0 * DM, kb + o1 * 512);
    GLOAD16(srcV + (size_t)kt * 4096 + o0 * 512, vb + o0 * 512);
    GLOAD16(srcV + (size_t)kt * 4096 + o1 * 512, vb + o1 * 512);
    __syncthreads();   // staged data visible (barrier drains vmcnt)

    // S^T = K.Q^T for both q-groups: 16 MFMA, ka fragments shared
    v4f s0[4], s1[4];
    #pragma unroll
    for (int g = 0; g < 4; ++g) {
      s0[g] = (v4f){0.f, 0.f, 0.f, 0.f};
      s1[g] = (v4f){0.f, 0.f, 0.f, 0.f};
    }
    #pragma unroll
    for (int g = 0; g < 4; ++g) {
      const v8s ka0 = *(const v8s*)(kb + (g*2 + 0) * 512 + lane * 8);
      const v8s ka1 = *(const v8s*)(kb + (g*2 + 1) * 512 + lane * 8);
      s0[g] = __builtin_amdgcn_mfma_f32_16x16x32_bf16(ka0, qf00, s0[g], 0, 0, 0);
      s0[g] = __builtin_amdgcn_mfma_f32_16x16x32_bf16(ka1, qf01, s0[g], 0, 0, 0);
      s1[g] = __builtin_amdgcn_mfma_f32_16x16x32_bf16(ka0, qf10, s1[g], 0, 0, 0);
      s1[g] = __builtin_amdgcn_mfma_f32_16x16x32_bf16(ka1, qf11, s1[g], 0, 0, 0);
    }

    // no-max softmax (exp2 domain) -> in-register PV B-fragments, both groups
    v4s pf0[4], pf1[4];
    float ls0 = 0.f, ls1 = 0.f;
    #pragma unroll
    for (int g = 0; g < 4; ++g) {
      float e0 = __builtin_amdgcn_exp2f(s0[g][0]);
      float e1 = __builtin_amdgcn_exp2f(s0[g][1]);
      float e2 = __builtin_amdgcn_exp2f(s0[g][2]);
      float e3 = __builtin_amdgcn_exp2f(s0[g][3]);
      ls0 += (e0 + e1) + (e2 + e3);
      union { v4s s; uint2 u; } pk;
      pk.u.x = pack2_bf16(e0, e1);
      pk.u.y = pack2_bf16(e2, e3);
      pf0[g] = pk.s;
      float f0 = __builtin_amdgcn_exp2f(s1[g][0]);
      float f1 = __builtin_amdgcn_exp2f(s1[g][1]);
      float f2 = __builtin_amdgcn_exp2f(s1[g][2]);
      float f3 = __builtin_amdgcn_exp2f(s1[g][3]);
      ls1 += (f0 + f1) + (f2 + f3);
      union { v4s s; uint2 u; } pk2;
      pk2.u.x = pack2_bf16(f0, f1);
      pk2.u.y = pack2_bf16(f2, f3);
      pf1[g] = pk2.s;
    }
    ls0 += __shfl_xor(ls0, 16, 64);
    ls0 += __shfl_xor(ls0, 32, 64);
    lrun0 += ls0;
    ls1 += __shfl_xor(ls1, 16, 64);
    ls1 += __shfl_xor(ls1, 32, 64);
    lrun1 += ls1;

    // O^T += V^T . P : 32 MFMA (16x16x16), vf fragments shared across groups
    #pragma unroll
    for (int dg = 0; dg < 4; ++dg) {
      #pragma unroll
      for (int g = 0; g < 4; ++g) {
        const v4s vf = *(const v4s*)(vb + (g*4 + dg) * 256 + quad * 64 + r16 * 4);
        acc0[dg] = MFMA16(vf, pf0[g], acc0[dg]);
        acc1[dg] = MFMA16(vf, pf1[g], acc1[dg]);
      }
    }
  }

  // ---- in-LDS cross-half combine (rows padded to FSTR floats: conflict-free) ----
  __syncthreads();   // all waves done with K/V LDS
  float* facc = (float*)smem;
  const int row0 = w4 * 32 + r16, row1 = row0 + 16;
  if (half == 1) {
    #pragma unroll
    for (int dg = 0; dg < 4; ++dg) {
      *(v4f*)(facc + row0 * FSTR + dg * 16 + quad * 4) = acc0[dg];
      *(v4f*)(facc + row1 * FSTR + dg * 16 + quad * 4) = acc1[dg];
    }
    if (quad == 0) { lred[row0] = lrun0; lred[row1] = lrun1; }
  }
  __syncthreads();
  if (half == 0) {
    const float inv0 = 1.f / (lrun0 + lred[row0]);
    const float inv1 = 1.f / (lrun1 + lred[row1]);
    ushort_t* gO = O + (size_t)b * SEQ * DM + h * HD;
    #pragma unroll
    for (int dg = 0; dg < 4; ++dg) {
      const v4f u0 = acc0[dg] + *(const v4f*)(facc + row0 * FSTR + dg * 16 + quad * 4);
      const v4f u1 = acc1[dg] + *(const v4f*)(facc + row1 * FSTR + dg * 16 + quad * 4);
      ushort4 o4;
      o4.x = f2bf(u0[0] * inv0);
      o4.y = f2bf(u0[1] * inv0);
      o4.z = f2bf(u0[2] * inv0);
      o4.w = f2bf(u0[3] * inv0);
      *(ushort4*)(gO + (size_t)qt0 * DM + dg*16 + quad*4) = o4;
      ushort4 o5;
      o5.x = f2bf(u1[0] * inv1);
      o5.y = f2bf(u1[1] * inv1);
      o5.z = f2bf(u1[2] * inv1);
      o5.w = f2bf(u1[3] * inv1);
      *(ushort4*)(gO + (size_t)qt1 * DM + dg*16 + quad*4) = o5;
    }
  }
}

extern "C" void kernel_launch(void* const* d_in, const int* in_sizes, int n_in,
                              void* d_out, int out_size, void* d_ws, size_t ws_size,
                              hipStream_t stream) {
  const float* x     = (const float*)d_in[0];
  const float* gamma = (const float*)d_in[1];
  const float* beta  = (const float*)d_in[2];
  const float* wq    = (const float*)d_in[3];
  const float* bq    = (const float*)d_in[4];
  const float* wk    = (const float*)d_in[5];
  const float* bk    = (const float*)d_in[6];
  const float* wv    = (const float*)d_in[7];
  const float* bv    = (const float*)d_in[8];
  const float* wo    = (const float*)d_in[9];
  const float* bo    = (const float*)d_in[10];
  float* out = (float*)d_out;

  unsigned char* w8 = (unsigned char*)d_ws;
  const size_t MB = 1024 * 1024;
  ushort_t* xn  = (ushort_t*)(w8 + 0 * MB);   // 8 MB; reused as attention output
  ushort_t* qb  = (ushort_t*)(w8 + 8 * MB);
  ushort_t* kb  = (ushort_t*)(w8 + 16 * MB);
  ushort_t* vt  = (ushort_t*)(w8 + 24 * MB);
  ushort_t* wtq = (ushort_t*)(w8 + 32 * MB);
  ushort_t* wtk = (ushort_t*)(w8 + 34 * MB);
  ushort_t* wtv = (ushort_t*)(w8 + 36 * MB);
  ushort_t* wto = (ushort_t*)(w8 + 38 * MB);
  ushort_t* ob  = xn;

  prep_kernel<<<dim3(NTOK + 1024), dim3(256), 0, stream>>>(
      x, gamma, beta, xn, wq, wk, wv, wo, wtq, wtk, wtv, wto);
  gemm_qkv<<<dim3(768), dim3(256), 0, stream>>>(xn, wtq, wtk, wtv, bq, bk, bv, qb, kb, vt);
  attn_kernel<<<dim3(512), dim3(512), 0, stream>>>(qb, kb, vt, ob);
  gemm_out<<<dim3(1024), dim3(256), 0, stream>>>(ob, wto, bo, out);
}